// Round 3
// baseline (3690.776 us; speedup 1.0000x reference)
//
#include <hip/hip_runtime.h>
#include <math.h>

// B=256, T=2048, D=64, U=128, 4U=512, COND=32
namespace {
constexpr int kB    = 256;
constexpr int kT    = 2048;
constexpr int kD    = 64;
constexpr int kU    = 128;
constexpr int kCOND = 32;
constexpr int kG    = 16;    // batch elements per block (= MFMA M rows, no waste)
constexpr int kCH   = 16;    // timesteps per x chunk
// LDS layout (byte offsets into one char array):
//   xs  : ring*32768 + bb*2048 + tt*128 + d*2      (^ (bb&7)<<4), 2*32 KB
//   hbuf: 65536 + cur*4096 + bb*256 + u*2          (^ (bb&7)<<4), 2*4 KB
constexpr int kXsRing = 32768;
constexpr int kHOff   = 65536;
constexpr int kLds    = 65536 + 8192;
}

typedef _Float16 f16x8 __attribute__((ext_vector_type(8)));
typedef _Float16 f16x4 __attribute__((ext_vector_type(4)));
typedef float    f32x4 __attribute__((ext_vector_type(4)));

__device__ __forceinline__ float sig_(float z) {
    return 1.0f / (1.0f + __expf(-z));
}
__device__ __forceinline__ float tanh_(float z) {
    float ez = __expf(-2.0f * fabsf(z));
    float t  = (1.0f - ez) / (1.0f + ez);
    return copysignf(t, z);
}
// pin a 16B fragment so the allocator cannot rematerialize its global loads
__device__ __forceinline__ void pin4_(f16x8& w) {
    f32x4 t = __builtin_bit_cast(f32x4, w);
    asm volatile("" : "+v"(t));
    w = __builtin_bit_cast(f16x8, t);
}

// 16 batch elements per block (16 blocks total): MFMA M-rows = 16 REAL
// batches instead of the old 16-way m-broadcast of one batch. Per the
// proven fragment rules (m89/m91):
//   A[m][k]: m = lane&15 (batch), k = 8*(lane>>4) + j  (per 32-K chunk)
//   B[n][k]: n = lane&15 (weight col within tile)
//   D[row][col]: row = 4*(lane>>4)+reg (batch), col = lane&15
// Wave w owns col-tiles {w, w+8, w+16, w+24} -> lane (q,c) holds all four
// gate preacts of (batch 4q+r, u = 16w+c) in acc[jt][r]; LSTM state
// c_reg[4] stays in-lane. h exchange via swizzled LDS + one lgkm-only
// barrier per step. x@Wk is computed ONE STEP AHEAD into preacc registers
// (its D-frag layout == the h-MFMA accumulator init), from an x chunk
// ring staged 16 steps ahead (prefetch in flight across barriers).
__global__ __launch_bounds__(512, 2)
void lstm_mfma(const float* __restrict__ x,     // [B,T,D]
               const float* __restrict__ cond,  // [B,COND]
               const float* __restrict__ Wc,    // [COND,U]
               const float* __restrict__ bc,    // [U]
               const float* __restrict__ Wk,    // [D,4U]
               const float* __restrict__ Uk,    // [U,4U]
               const float* __restrict__ bias,  // [4U]
               float* __restrict__ out) {       // [B,U]
    const int g    = blockIdx.x;   // batch group: batches 16g .. 16g+15
    const int tid  = threadIdx.x;
    const int lane = tid & 63;
    const int w    = tid >> 6;     // wave 0..7 -> u-tile w
    const int q    = lane >> 4;    // quad 0..3
    const int c    = lane & 15;
    const int u    = 16 * w + c;   // this lane's state column

    __shared__ __align__(16) char lds[kLds];

    // ---- B-frags: 4 tiles x 6 K-chunks, k = 32*kc + 8*q + j, col = 16t + c ----
    // kc 0..1 = Wk (K=64), kc 2..5 = Uk (K=128)
    f16x8 wfrag[4][6];
    float btile[4];
#pragma unroll
    for (int jt = 0; jt < 4; ++jt) {
        const int t   = w + 8 * jt;          // tile; jt = gate index (i,f,c~,o)
        const int col = 16 * t + c;
#pragma unroll
        for (int kc = 0; kc < 6; ++kc) {
            f16x8 f;
#pragma unroll
            for (int j = 0; j < 8; ++j) {
                const int k = 32 * kc + 8 * q + j;
                const float v = (k < kD) ? Wk[k * 512 + col]
                                         : Uk[(k - kD) * 512 + col];
                f[j] = (_Float16)v;
            }
            wfrag[jt][kc] = f;
        }
        btile[jt] = bias[col];
    }
#pragma unroll
    for (int jt = 0; jt < 4; ++jt)
#pragma unroll
        for (int kc = 0; kc < 6; ++kc) pin4_(wfrag[jt][kc]);

    // ---- initial state: c0[r] = h0 = bc[u] + cond[16g+4q+r,:] @ Wc[:,u] ----
    float c_reg[4], h_out[4];
#pragma unroll
    for (int r = 0; r < 4; ++r) {
        const int bb = 4 * q + r;
        float a = bc[u];
        const float* cr = cond + (size_t)(kG * g + bb) * kCOND;
#pragma unroll
        for (int kk = 0; kk < kCOND; ++kk) a = fmaf(cr[kk], Wc[kk * kU + u], a);
        c_reg[r] = a;
        h_out[r] = 0.0f;
        int byte = kHOff + bb * 256 + u * 2;
        byte ^= (bb & 7) << 4;
        *(_Float16*)(lds + byte) = (_Float16)a;
    }

    // ---- x staging: thread owns batch bb_s, 8 float4 per chunk ----
    const int bb_s = tid >> 5;           // 0..15
    const int l32  = tid & 31;
    const float* xsrc = x + (size_t)(kG * g + bb_s) * kT * kD;

    // stage chunk 0 (t = 0..15) into ring 0
    {
        float4 v[8];
#pragma unroll
        for (int l = 0; l < 8; ++l)
            v[l] = *(const float4*)(xsrc + l32 * 4 + l * 128);
#pragma unroll
        for (int l = 0; l < 8; ++l) {
            const int flat = l32 * 4 + l * 128;
            int byte = bb_s * 2048 + (flat >> 6) * 128 + (flat & 63) * 2;
            byte ^= (bb_s & 7) << 4;
            *(f16x4*)(lds + byte) =
                (f16x4){(_Float16)v[l].x, (_Float16)v[l].y,
                        (_Float16)v[l].z, (_Float16)v[l].w};
        }
    }
    __syncthreads();

    // x-preact for step tn: preacc[jt] = bias + x[.,tn,:] @ Wk (D rows = batches)
    auto xpre = [&](int tn, f32x4* pre) {
        const int rn = (tn >> 4) & 1, ti = tn & 15;
        f16x8 ax[2];
#pragma unroll
        for (int kc = 0; kc < 2; ++kc) {
            int byte = rn * kXsRing + c * 2048 + ti * 128 + 64 * kc + 16 * q;
            byte ^= (c & 7) << 4;
            ax[kc] = *(const f16x8*)(lds + byte);
        }
#pragma unroll
        for (int jt = 0; jt < 4; ++jt)
            pre[jt] = (f32x4){btile[jt], btile[jt], btile[jt], btile[jt]};
#pragma unroll
        for (int kc = 0; kc < 2; ++kc)
#pragma unroll
            for (int jt = 0; jt < 4; ++jt)
                pre[jt] = __builtin_amdgcn_mfma_f32_16x16x32_f16(
                    ax[kc], wfrag[jt][kc], pre[jt], 0, 0, 0);
    };

    f32x4 preacc[4];
    xpre(0, preacc);

    float4 xpf[8];                        // in-flight chunk prefetch

#pragma unroll 1
    for (int t = 0; t < kT; ++t) {
        const int tin  = t & (kCH - 1);
        const int ring = (t >> 4) & 1;
        const int cur  = t & 1;

        // issue next chunk's global loads (landed at tin==14)
        if (tin == 0) {
            int tb = t + kCH;
            if (tb > kT - kCH) tb = kT - kCH;   // tail: re-read last chunk, never used
#pragma unroll
            for (int l = 0; l < 8; ++l)
                xpf[l] = *(const float4*)(xsrc + (size_t)tb * kD + l32 * 4 + l * 128);
        }

        // h A-frags: A[m=batch][k], lane reads hbuf row c (swizzled, 2-way free)
        f16x8 afh[4];
#pragma unroll
        for (int kc = 0; kc < 4; ++kc) {
            int byte = kHOff + cur * 4096 + c * 256 + 64 * kc + 16 * q;
            byte ^= (c & 7) << 4;
            afh[kc] = *(const f16x8*)(lds + byte);
        }

        f32x4 acc[4];
#pragma unroll
        for (int jt = 0; jt < 4; ++jt) acc[jt] = preacc[jt];
#pragma unroll
        for (int kc = 0; kc < 4; ++kc)
#pragma unroll
            for (int jt = 0; jt < 4; ++jt)
                acc[jt] = __builtin_amdgcn_mfma_f32_16x16x32_f16(
                    afh[kc], wfrag[jt][2 + kc], acc[jt], 0, 0, 0);

        // next step's x-preact (independent of h -> overlaps h-MFMA/activation)
        if (t < kT - 1) xpre(t + 1, preacc);

        // activations: 4 independent (batch 4q+r) chains, all gates in-lane
#pragma unroll
        for (int r = 0; r < 4; ++r) {
            const float iv = sig_(acc[0][r]);
            const float fv = sig_(acc[1][r]);
            const float cb = tanh_(acc[2][r]);
            const float ov = sig_(acc[3][r]);
            c_reg[r] = fmaf(fv, c_reg[r], iv * cb);
            h_out[r] = ov * tanh_(c_reg[r]);
            const int bb = 4 * q + r;
            int byte = kHOff + (cur ^ 1) * 4096 + bb * 256 + u * 2;
            byte ^= (bb & 7) << 4;
            *(_Float16*)(lds + byte) = (_Float16)h_out[r];
        }

        // land the prefetched chunk (compiler inserts the vmcnt wait here)
        if (tin == kCH - 2) {
#pragma unroll
            for (int l = 0; l < 8; ++l) {
                const int flat = l32 * 4 + l * 128;
                int byte = (ring ^ 1) * kXsRing + bb_s * 2048 +
                           (flat >> 6) * 128 + (flat & 63) * 2;
                byte ^= (bb_s & 7) << 4;
                *(f16x4*)(lds + byte) =
                    (f16x4){(_Float16)xpf[l].x, (_Float16)xpf[l].y,
                            (_Float16)xpf[l].z, (_Float16)xpf[l].w};
            }
        }

        // LDS-only barrier: never drains vmcnt -> x prefetch stays in flight
        asm volatile("s_waitcnt lgkmcnt(0)\n\ts_barrier" ::: "memory");
    }

#pragma unroll
    for (int r = 0; r < 4; ++r)
        out[(size_t)(kG * g + 4 * q + r) * kU + u] = h_out[r];
}

extern "C" void kernel_launch(void* const* d_in, const int* in_sizes, int n_in,
                              void* d_out, int out_size, void* d_ws, size_t ws_size,
                              hipStream_t stream) {
    const float* x    = (const float*)d_in[0];
    const float* cond = (const float*)d_in[1];
    const float* Wc   = (const float*)d_in[2];
    const float* bc   = (const float*)d_in[3];
    const float* Wk   = (const float*)d_in[4];
    const float* Uk   = (const float*)d_in[5];
    const float* b    = (const float*)d_in[6];
    float* out = (float*)d_out;

    lstm_mfma<<<dim3(kB / kG), dim3(512), 0, stream>>>(x, cond, Wc, bc, Wk, Uk, b, out);
}

// Round 4
// 1827.704 us; speedup vs baseline: 2.0194x; 2.0194x over previous
//
#include <hip/hip_runtime.h>
#include <math.h>

// B=256, T=2048, D=64, U=128, 4U=512, COND=32
namespace {
constexpr int kB    = 256;
constexpr int kT    = 2048;
constexpr int kD    = 64;
constexpr int kU    = 128;
constexpr int kCOND = 32;
// LDS layout (byte offsets):
//   xg  : 2 slots of [16][516] f32  (x@Wk + bias, rows = timestep-in-chunk)
//   xs  : 2 slots of [16][64] f16   (x chunk, swizzled)
//   hbuf: 2 x [128] f16
constexpr int kXGS    = 516;               // xg row stride, floats (516%32=4)
constexpr int kXgSlot = 16 * kXGS * 4;     // 33024 B
constexpr int kXgOff  = 0;
constexpr int kXsOff  = 2 * kXgSlot;       // 66048 (multiple of 128)
constexpr int kXsSlot = 2048;
constexpr int kHOff   = kXsOff + 2 * kXsSlot;  // 70144
constexpr int kLds    = kHOff + 512;       // 70656
}

typedef _Float16 f16x8 __attribute__((ext_vector_type(8)));
typedef _Float16 f16x4 __attribute__((ext_vector_type(4)));
typedef float    f32x4 __attribute__((ext_vector_type(4)));

__device__ __forceinline__ float sig_(float z) {
    return 1.0f / (1.0f + __expf(-z));
}
__device__ __forceinline__ float tanh_(float z) {
    float ez = __expf(-2.0f * fabsf(z));
    float t  = (1.0f - ez) / (1.0f + ez);
    return copysignf(t, z);
}
__device__ __forceinline__ void pin4_(f16x8& w) {
    f32x4 t = __builtin_bit_cast(f32x4, w);
    asm volatile("" : "+v"(t));
    w = __builtin_bit_cast(f16x8, t);
}

// Pack Wk into MFMA B-fragment order (f16) in the workspace:
// idx = (((tile*2+kc)*4+q)*16+c)*8+j  ->  Wk[(32kc+8q+j)*512 + 16*tile+c]
__global__ __launch_bounds__(512)
void pack_wk(const float* __restrict__ Wk, _Float16* __restrict__ wsp) {
    const int idx  = blockIdx.x * 512 + threadIdx.x;   // 0..32767
    const int j    = idx & 7;
    const int c    = (idx >> 3) & 15;
    const int q    = (idx >> 7) & 3;
    const int kc   = (idx >> 9) & 1;
    const int tile = idx >> 10;
    wsp[idx] = (_Float16)Wk[(32 * kc + 8 * q + j) * 512 + 16 * tile + c];
}

// One WG (768 thr = 12 waves) per batch element, persistent over T steps.
// WAVE SPECIALIZATION (breaks the phase lock that capped R1/R2 at ~1886
// cyc/step): each SIMD hosts 2 CONSUMER waves + 1 PRODUCER wave in
// different phases, so producer issue overlaps the consumers' serial
// h-chain (ds_read h -> 4-deep MFMA -> activations -> ds_write -> barrier).
//
//  - consumers (waves 0..7): m-broadcast h@Uk only: 16 MFMAs/step, acc
//    initialized from xg (x-preact + bias, produced a chunk ahead).
//    Wave w owns N-tiles {w,w+8,w+16,w+24} -> all 4 gates of u=16w+c
//    land in-lane (proven m91 mapping).
//  - producers (waves 8..11): per 16-step chunk: tin==0 issue global x
//    loads (chunk k+2), tin==4 land them into swizzled xs, tin 6..9 run
//    the chunk-GEMM for chunk k+1 with M = 16 REAL timesteps (2 of this
//    wave's 8 col-tiles per step; Wk frags reloaded per chunk from the
//    packed L2-resident workspace copy -> no register-union blowup).
// One lgkm-only barrier per step (never drains vmcnt).
__global__ __launch_bounds__(768, 3)
void lstm_mfma(const float* __restrict__ x,     // [B,T,D]
               const float* __restrict__ cond,  // [B,COND]
               const float* __restrict__ Wc,    // [COND,U]
               const float* __restrict__ bc,    // [U]
               const float* __restrict__ Wk,    // [D,4U] (fallback path)
               const float* __restrict__ Uk,    // [U,4U]
               const float* __restrict__ bias,  // [4U]
               const _Float16* __restrict__ wkp, // packed Wk frags (or null)
               float* __restrict__ out) {       // [B,U]
    const int b    = blockIdx.x;
    const int tid  = threadIdx.x;
    const int lane = tid & 63;
    const int w    = tid >> 6;     // wave 0..11
    const int q    = lane >> 4;    // quad 0..3
    const int c    = lane & 15;

    __shared__ __align__(16) char lds[kLds];
    const float* xb = x + (size_t)b * kT * kD;

    // ---------- role-specific persistent state ----------
    f16x8 wfragU[4][4];            // consumers: Uk frags (col=16*(w+8jt)+c)
    float c_reg = 0.0f, h_out = 0.0f;
    float btileP[8];               // producers: bias for their 8 tiles
    float4 pv0, pv1;               // producer prologue staging

    const bool packed = (wkp != nullptr);

    // producer helpers
    auto loadW = [&](int tile, int kc) -> f16x8 {
        if (packed) {
            return *(const f16x8*)&wkp[(size_t)((((tile * 2 + kc) * 4 + q) * 16 + c) * 8)];
        } else {
            f16x8 f;
            const int col = 16 * tile + c;
#pragma unroll
            for (int j = 0; j < 8; ++j)
                f[j] = (_Float16)Wk[(32 * kc + 8 * q + j) * 512 + col];
            return f;
        }
    };
    auto loadAx = [&](int sslot, f16x8* ax) {
#pragma unroll
        for (int kc = 0; kc < 2; ++kc) {
            int byte = kXsOff + sslot * kXsSlot + c * 128 + 64 * kc + 16 * q;
            byte ^= (c & 7) << 4;
            ax[kc] = *(const f16x8*)(lds + byte);
        }
    };
    // chunk-GEMM for tiles [i0,i1) of this producer wave: D rows = timesteps
    auto pgemm = [&](int dslot, int i0, int i1, const f16x8* ax) {
#pragma unroll
        for (int i = i0; i < i1; ++i) {
            const int tile = 8 * (w - 8) + i;
            const int col  = 16 * tile + c;
            const f16x8 wf0 = loadW(tile, 0);
            const f16x8 wf1 = loadW(tile, 1);
            f32x4 acc = (f32x4){btileP[i], btileP[i], btileP[i], btileP[i]};
            acc = __builtin_amdgcn_mfma_f32_16x16x32_f16(ax[0], wf0, acc, 0, 0, 0);
            acc = __builtin_amdgcn_mfma_f32_16x16x32_f16(ax[1], wf1, acc, 0, 0, 0);
            float* dst = (float*)(lds + kXgOff + dslot * kXgSlot);
#pragma unroll
            for (int r = 0; r < 4; ++r)
                dst[(4 * q + r) * kXGS + col] = acc[r];
        }
    };

    // ---------- prologue ----------
    if (w < 8) {
        const int u = 16 * w + c;
#pragma unroll
        for (int jt = 0; jt < 4; ++jt) {
            const int col = 16 * (w + 8 * jt) + c;
#pragma unroll
            for (int kc = 0; kc < 4; ++kc) {
                f16x8 f;
#pragma unroll
                for (int j = 0; j < 8; ++j)
                    f[j] = (_Float16)Uk[(32 * kc + 8 * q + j) * 512 + col];
                wfragU[jt][kc] = f;
            }
        }
#pragma unroll
        for (int jt = 0; jt < 4; ++jt)
#pragma unroll
            for (int kc = 0; kc < 4; ++kc) pin4_(wfragU[jt][kc]);

        // c0 = h0 = bc[u] + cond[b,:] @ Wc[:,u]
        float a = bc[u];
        const float* cr = cond + (size_t)b * kCOND;
#pragma unroll
        for (int kk = 0; kk < kCOND; ++kk) a = fmaf(cr[kk], Wc[kk * kU + u], a);
        c_reg = a;
        if (q == 0) *(_Float16*)(lds + kHOff + 2 * u) = (_Float16)a;
    } else {
        const int pw = w - 8;
        const int pt = tid - 512;          // 0..255, owns 4 floats/chunk
#pragma unroll
        for (int i = 0; i < 8; ++i) btileP[i] = bias[16 * (8 * pw + i) + c];
        pv0 = *(const float4*)&xb[pt * 4];          // chunk 0
        pv1 = *(const float4*)&xb[1024 + pt * 4];   // chunk 1
        // land chunk 0 into xs[0] (swizzled)
        const int row = pt >> 4, d0 = (pt & 15) * 4;
        int byte = kXsOff + row * 128 + d0 * 2;
        byte ^= (row & 7) << 4;
        *(f16x4*)(lds + byte) = (f16x4){(_Float16)pv0.x, (_Float16)pv0.y,
                                        (_Float16)pv0.z, (_Float16)pv0.w};
    }
    __syncthreads();
    if (w >= 8) {
        f16x8 ax0[2];
        loadAx(0, ax0);
        pgemm(0, 0, 8, ax0);               // xg[0] = chunk-0 preacts
        const int pt = tid - 512;
        const int row = pt >> 4, d0 = (pt & 15) * 4;
        int byte = kXsOff + kXsSlot + row * 128 + d0 * 2;   // xs[1] = chunk 1
        byte ^= (row & 7) << 4;
        *(f16x4*)(lds + byte) = (f16x4){(_Float16)pv1.x, (_Float16)pv1.y,
                                        (_Float16)pv1.z, (_Float16)pv1.w};
    }
    __syncthreads();

    // ---------- main loop ----------
    float4 xpf;
    f16x8  axm[2];                         // producer A-frags, live tin 6..9

#pragma unroll 1
    for (int t = 0; t < kT; ++t) {
        const int tin = t & 15;
        const int k   = t >> 4;
        const int cur = t & 1;

        if (w < 8) {
            // ---- consumer ----
            f16x8 afh[4];
#pragma unroll
            for (int kc = 0; kc < 4; ++kc)
                afh[kc] = *(const f16x8*)(lds + kHOff + cur * 256 + 64 * kc + 16 * q);

            f32x4 acc[4];
#pragma unroll
            for (int jt = 0; jt < 4; ++jt) {
                const float g = *(const float*)(lds + kXgOff + (k & 1) * kXgSlot +
                                                (tin * kXGS + 16 * (w + 8 * jt) + c) * 4);
                acc[jt] = (f32x4){g, g, g, g};
            }

            __builtin_amdgcn_s_setprio(1);
#pragma unroll
            for (int kc = 0; kc < 4; ++kc)
#pragma unroll
                for (int jt = 0; jt < 4; ++jt)
                    acc[jt] = __builtin_amdgcn_mfma_f32_16x16x32_f16(
                        afh[kc], wfragU[jt][kc], acc[jt], 0, 0, 0);
            __builtin_amdgcn_s_setprio(0);

            const float iv = sig_(acc[0][0]);
            const float fv = sig_(acc[1][0]);
            const float cb = tanh_(acc[2][0]);
            const float ov = sig_(acc[3][0]);
            c_reg = fmaf(fv, c_reg, iv * cb);
            h_out = ov * tanh_(c_reg);
            if (q == 0)
                *(_Float16*)(lds + kHOff + (cur ^ 1) * 256 + 2 * (16 * w + c)) =
                    (_Float16)h_out;
        } else {
            // ---- producer ----
            const int pt = tid - 512;
            if (tin == 0) {
                int kn = k + 2; if (kn > 127) kn = 127;   // tail: staged, never GEMMed
                xpf = *(const float4*)&xb[(size_t)kn * 1024 + pt * 4];
            } else if (tin == 4) {
                // land chunk k+2 into xs[(k+2)&1] == xs[k&1]
                const int row = pt >> 4, d0 = (pt & 15) * 4;
                int byte = kXsOff + (k & 1) * kXsSlot + row * 128 + d0 * 2;
                byte ^= (row & 7) << 4;
                *(f16x4*)(lds + byte) = (f16x4){(_Float16)xpf.x, (_Float16)xpf.y,
                                                (_Float16)xpf.z, (_Float16)xpf.w};
            } else if (tin == 6 && k < 127) {
                loadAx((k + 1) & 1, axm);
                pgemm((k + 1) & 1, 0, 2, axm);
            } else if (tin == 7 && k < 127) {
                pgemm((k + 1) & 1, 2, 4, axm);
            } else if (tin == 8 && k < 127) {
                pgemm((k + 1) & 1, 4, 6, axm);
            } else if (tin == 9 && k < 127) {
                pgemm((k + 1) & 1, 6, 8, axm);
            }
        }

        // LDS-only barrier: never drains vmcnt -> x prefetch stays in flight
        asm volatile("s_waitcnt lgkmcnt(0)\n\ts_barrier" ::: "memory");
    }

    if (w < 8 && q == 0) out[(size_t)b * kU + 16 * w + c] = h_out;
}

extern "C" void kernel_launch(void* const* d_in, const int* in_sizes, int n_in,
                              void* d_out, int out_size, void* d_ws, size_t ws_size,
                              hipStream_t stream) {
    const float* x    = (const float*)d_in[0];
    const float* cond = (const float*)d_in[1];
    const float* Wc   = (const float*)d_in[2];
    const float* bc   = (const float*)d_in[3];
    const float* Wk   = (const float*)d_in[4];
    const float* Uk   = (const float*)d_in[5];
    const float* b    = (const float*)d_in[6];
    float* out = (float*)d_out;

    _Float16* wkp = nullptr;
    if (d_ws && ws_size >= 65536) {
        wkp = (_Float16*)d_ws;
        pack_wk<<<dim3(64), dim3(512), 0, stream>>>(Wk, wkp);
    }
    lstm_mfma<<<dim3(kB), dim3(768), 0, stream>>>(x, cond, Wc, bc, Wk, Uk, b,
                                                  wkp, out);
}

// Round 6
// 1664.380 us; speedup vs baseline: 2.2175x; 1.0981x over previous
//
#include <hip/hip_runtime.h>
#include <math.h>

// B=256, T=2048, D=64, U=128, 4U=512, COND=32
namespace {
constexpr int kB    = 256;
constexpr int kT    = 2048;
constexpr int kD    = 64;
constexpr int kU    = 128;
constexpr int kCOND = 32;
constexpr int kCH   = 16;                      // timesteps per x chunk
constexpr int kXGS  = 520;                     // xg row stride (floats)
// LDS layout (byte offsets into one char array):
constexpr int kXgSlot = kCH * kXGS * 4;        // 33280 B
constexpr int kXgOff  = 0;                     // xg: 2 slots
constexpr int kXsOff  = 2 * kXgSlot;           // 66560; xs: 2 x [16][64] f16 swz
constexpr int kXsSlot = kCH * kD * 2;          // 2048 B
constexpr int kHOff   = kXsOff + 2 * kXsSlot;  // 70656; hbuf: 2 x [128] f16
constexpr int kLds    = kHOff + 512;           // 71168
}

typedef _Float16 f16x8 __attribute__((ext_vector_type(8)));
typedef _Float16 f16x2 __attribute__((ext_vector_type(2)));
typedef float    f32x4 __attribute__((ext_vector_type(4)));

__device__ __forceinline__ float sig_(float z) {
    return 1.0f / (1.0f + __expf(-z));
}
__device__ __forceinline__ float tanh_(float z) {
    float ez = __expf(-2.0f * fabsf(z));
    float t  = (1.0f - ez) / (1.0f + ez);
    return copysignf(t, z);
}
// pin a 16B fragment so the allocator cannot rematerialize its global loads
__device__ __forceinline__ void pin4_(f16x8& w) {
    f32x4 t = __builtin_bit_cast(f32x4, w);
    asm volatile("" : "+v"(t));
    w = __builtin_bit_cast(f16x8, t);
}

// One WG (512 thr = 8 waves) per batch element, persistent over T steps.
// R1 shell (uniform waves, 96-reg wfrag, single lgkm-only barrier/step) +
// three bubble-killers:
//  1) x@Wk+bias precomputed per 16-step chunk into LDS xg, and the NEXT
//     step's 4 gate-init values prefetched into REGISTERS (xgn) at the end
//     of each step -> the h-MFMA chain starts with zero acc-init latency.
//  2) the chunk-GEMM (8 MFMAs + 16 stores, M = 16 real timesteps) runs
//     STAGGERED: wave w at tin==2w+1, same wave as the h-chain, using the
//     Wk frags it already holds -> fills the h-chain's dependency bubbles
//     (intra-wave ILP), no spike step, no producer/consumer register union.
//  3) h@Uk tree-split: accA = xgn + kc0 + kc1, accB = 0 + kc2 + kc3,
//     g = accA[0] + accB[0] -> MFMA chain depth 4 -> 2.
// x staged in a 2-chunk LDS ring (XOR-swizzled rows); global float2 loads
// issued at tin==0 (chunk k+2), landed at tin==14; barrier never drains
// vmcnt so they stay in flight.
// xg cross-wave safety: wave w's xgn prefetch reads ONLY the xg columns
// wave w itself wrote in its own xgemm (same-wave program order).
__global__ __launch_bounds__(512, 2)
void lstm_mfma(const float* __restrict__ x,     // [B,T,D]
               const float* __restrict__ cond,  // [B,COND]
               const float* __restrict__ Wc,    // [COND,U]
               const float* __restrict__ bc,    // [U]
               const float* __restrict__ Wk,    // [D,4U]
               const float* __restrict__ Uk,    // [U,4U]
               const float* __restrict__ bias,  // [4U]
               float* __restrict__ out) {       // [B,U]
    const int b    = blockIdx.x;
    const int tid  = threadIdx.x;
    const int lane = tid & 63;
    const int w    = tid >> 6;     // wave 0..7
    const int q    = lane >> 4;    // quad 0..3
    const int c    = lane & 15;
    const int u    = 16 * w + c;   // this lane's state element

    __shared__ __align__(16) char lds[kLds];

    // ---- B-frags: 4 tiles x 6 K-chunks, k = 32*kc + 8*q + j, col = 16t + c ----
    // kc 0..1 = Wk (K=64), kc 2..5 = Uk (K=128)
    f16x8 wfrag[4][6];
    float btile[4];
#pragma unroll
    for (int jt = 0; jt < 4; ++jt) {
        const int t   = w + 8 * jt;          // tile; jt = gate index (i,f,c~,o)
        const int col = 16 * t + c;
#pragma unroll
        for (int kc = 0; kc < 6; ++kc) {
            f16x8 f;
#pragma unroll
            for (int j = 0; j < 8; ++j) {
                const int k = 32 * kc + 8 * q + j;
                const float v = (k < kD) ? Wk[k * 512 + col]
                                         : Uk[(k - kD) * 512 + col];
                f[j] = (_Float16)v;
            }
            wfrag[jt][kc] = f;
        }
        btile[jt] = bias[col];
    }
#pragma unroll
    for (int jt = 0; jt < 4; ++jt)
#pragma unroll
        for (int kc = 0; kc < 6; ++kc) pin4_(wfrag[jt][kc]);

    // chunk-GEMM for this wave's 4 tiles: xg[slot] cols {16(w+8jt)+c} =
    // bias + xs[slot] @ Wk. A rows = 16 REAL timesteps (lane m = c reads
    // timestep-row c of the swizzled chunk). D rows 4q+r = timesteps.
    auto xgemm = [&](int slot) {
        f16x8 ax[2];
#pragma unroll
        for (int kc = 0; kc < 2; ++kc) {
            int byte = kXsOff + slot * kXsSlot + c * 128 + 64 * kc + 16 * q;
            byte ^= (c & 7) << 4;
            ax[kc] = *(const f16x8*)(lds + byte);
        }
#pragma unroll
        for (int jt = 0; jt < 4; ++jt) {
            f32x4 acc = (f32x4){btile[jt], btile[jt], btile[jt], btile[jt]};
            acc = __builtin_amdgcn_mfma_f32_16x16x32_f16(ax[0], wfrag[jt][0], acc, 0, 0, 0);
            acc = __builtin_amdgcn_mfma_f32_16x16x32_f16(ax[1], wfrag[jt][1], acc, 0, 0, 0);
            float* dst = (float*)(lds + kXgOff + slot * kXgSlot);
            const int col = 16 * (w + 8 * jt) + c;
#pragma unroll
            for (int r = 0; r < 4; ++r)
                dst[(4 * q + r) * kXGS + col] = acc[r];
        }
    };

    // x chunk staging: thread owns floats [2tid, 2tid+1] of each 1024-float chunk
    const int srow = tid >> 5;             // timestep row in chunk
    const int sd   = (tid & 31) * 2;       // d offset
    const float* xb = x + (size_t)b * kT * kD;
    auto land = [&](int slot, float2 v) {
        int byte = kXsOff + slot * kXsSlot + srow * 128 + sd * 2;
        byte ^= (srow & 7) << 4;
        *(f16x2*)(lds + byte) = (f16x2){(_Float16)v.x, (_Float16)v.y};
    };

    // ---- initial state: c0 = h0 = bc[u] + cond[b,:] @ Wc[:,u] ----
    float c_reg;
    {
        float a = bc[u];
        const float* cr = cond + (size_t)b * kCOND;
#pragma unroll
        for (int kk = 0; kk < kCOND; ++kk) a = fmaf(cr[kk], Wc[kk * kU + u], a);
        c_reg = a;
        if (q == 0) *(_Float16*)(lds + kHOff + 2 * u) = (_Float16)a;
    }

    // ---- prologue: chunk 0 staged+GEMMed, chunk 1 staged ----
    land(0, *(const float2*)&xb[2 * tid]);
    __syncthreads();
    xgemm(0);
    land(1, *(const float2*)&xb[1024 + 2 * tid]);
    __syncthreads();

    // prefetch step-0 acc-init (this wave's own xg cols, written by itself)
    float xgn[4];
#pragma unroll
    for (int jt = 0; jt < 4; ++jt)
        xgn[jt] = *(const float*)(lds + kXgOff + (16 * (w + 8 * jt) + c) * 4);

    float  h_out = 0.0f;
    float2 xpf;

#pragma unroll 1
    for (int t = 0; t < kT; ++t) {
        const int tin = t & (kCH - 1);
        const int k   = t >> 4;
        const int cur = t & 1;

        // h A-frags first: the only step-critical LDS reads
        f16x8 afh[4];
#pragma unroll
        for (int kc = 0; kc < 4; ++kc)
            afh[kc] = *(const f16x8*)(lds + kHOff + cur * 256 + 64 * kc + 16 * q);

        // issue next chunk's global loads (landed at tin==14)
        if (tin == 0) {
            int kn = k + 2; if (kn > 127) kn = 127;   // tail: staged, never used
            xpf = *(const float2*)&xb[(size_t)kn * 1024 + 2 * tid];
        }

        // h-MFMA tree: accA = xgn + kc0 + kc1 ; accB = 0 + kc2 + kc3
        f32x4 accA[4], accB[4];
#pragma unroll
        for (int jt = 0; jt < 4; ++jt) {
            accA[jt] = (f32x4){xgn[jt], xgn[jt], xgn[jt], xgn[jt]};
            accB[jt] = (f32x4){0.0f, 0.0f, 0.0f, 0.0f};
        }
#pragma unroll
        for (int jt = 0; jt < 4; ++jt)
            accA[jt] = __builtin_amdgcn_mfma_f32_16x16x32_f16(
                afh[0], wfrag[jt][2], accA[jt], 0, 0, 0);
#pragma unroll
        for (int jt = 0; jt < 4; ++jt)
            accB[jt] = __builtin_amdgcn_mfma_f32_16x16x32_f16(
                afh[2], wfrag[jt][4], accB[jt], 0, 0, 0);
#pragma unroll
        for (int jt = 0; jt < 4; ++jt)
            accA[jt] = __builtin_amdgcn_mfma_f32_16x16x32_f16(
                afh[1], wfrag[jt][3], accA[jt], 0, 0, 0);
#pragma unroll
        for (int jt = 0; jt < 4; ++jt)
            accB[jt] = __builtin_amdgcn_mfma_f32_16x16x32_f16(
                afh[3], wfrag[jt][5], accB[jt], 0, 0, 0);

        // staggered chunk-GEMM: wave w computes its xg cols for chunk k+1
        // at tin == 2w+1 (independent of the h chain -> fills its bubbles)
        if (tin == 2 * w + 1 && k < 127) xgemm((k + 1) & 1);

        // gates: D row-constant -> reg 0; g = accA[0] + accB[0]
        const float iv = sig_(accA[0][0] + accB[0][0]);
        const float fv = sig_(accA[1][0] + accB[1][0]);
        const float cb = tanh_(accA[2][0] + accB[2][0]);
        const float ov = sig_(accA[3][0] + accB[3][0]);
        c_reg = fmaf(fv, c_reg, iv * cb);
        h_out = ov * tanh_(c_reg);
        if (q == 0)
            *(_Float16*)(lds + kHOff + (cur ^ 1) * 256 + 2 * u) = (_Float16)h_out;

        // prefetch next step's acc-init into registers (lgkm-covered by barrier)
        if (t < kT - 1) {
            const int t1 = t + 1;
            const char* src = lds + kXgOff + (((t1 >> 4) & 1) ? kXgSlot : 0) +
                              ((t1 & 15) * kXGS) * 4;
#pragma unroll
            for (int jt = 0; jt < 4; ++jt)
                xgn[jt] = *(const float*)(src + (16 * (w + 8 * jt) + c) * 4);
        }

        // land the prefetched x chunk (k+2) into xs[k&1]
        if (tin == kCH - 2) land(k & 1, xpf);

        // LDS-only barrier: never drains vmcnt -> x prefetch stays in flight
        asm volatile("s_waitcnt lgkmcnt(0)\n\ts_barrier" ::: "memory");
    }

    if (q == 0) out[(size_t)b * kU + u] = h_out;
}

extern "C" void kernel_launch(void* const* d_in, const int* in_sizes, int n_in,
                              void* d_out, int out_size, void* d_ws, size_t ws_size,
                              hipStream_t stream) {
    const float* x    = (const float*)d_in[0];
    const float* cond = (const float*)d_in[1];
    const float* Wc   = (const float*)d_in[2];
    const float* bc   = (const float*)d_in[3];
    const float* Wk   = (const float*)d_in[4];
    const float* Uk   = (const float*)d_in[5];
    const float* b    = (const float*)d_in[6];
    float* out = (float*)d_out;

    lstm_mfma<<<dim3(kB), dim3(512), 0, stream>>>(x, cond, Wc, bc, Wk, Uk, b, out);
}